// Round 2
// baseline (22706.873 us; speedup 1.0000x reference)
//
#include <hip/hip_runtime.h>
#include <cstdint>
#include <cstddef>

// GRU decoder: LAYERS=3, UNITS=1024, B=128, T=256, reset_after=True.
// R2: persistent per-layer recurrence kernel. 256 blocks (1/CU), U-slice
// LDS-resident across all 256 steps, grid barrier between steps.

#define UNITS 1024
#define U3 3072
#define BATCH 128
#define TSTEPS 256

typedef _Float16 h16;
typedef __attribute__((ext_vector_type(8))) _Float16 h16x8;
typedef __attribute__((ext_vector_type(4))) _Float16 h16x4;
typedef __attribute__((ext_vector_type(4))) float f32x4;

#define GAS __attribute__((address_space(1)))
#define LAS __attribute__((address_space(3)))
#define ASYNC16(g, l) __builtin_amdgcn_global_load_lds((const GAS unsigned int*)(g), (LAS unsigned int*)(l), 16, 0, 0)

__device__ __forceinline__ float sigmf(float x) { return 1.0f / (1.0f + __expf(-x)); }
__device__ __forceinline__ float tanhf_fast(float x) { return 2.0f / (1.0f + __expf(-2.0f * x)) - 1.0f; }

// input_seq [B,T,U] f32 -> x16 [T,B,U] f16
__global__ void k_cvt_x(const float* __restrict__ x, h16* __restrict__ xo) {
  const int m = blockIdx.x;            // out row = t*128 + b
  const int t = m >> 7, b = m & 127;
  const int u = threadIdx.x << 2;
  const float4 v = *(const float4*)(x + (size_t)((b << 8) + t) * UNITS + u);
  h16x4 o; o[0] = (h16)v.x; o[1] = (h16)v.y; o[2] = (h16)v.z; o[3] = (h16)v.w;
  *(h16x4*)(xo + (size_t)m * UNITS + u) = o;
}

// src [3][1024][3072] f32 -> dst [3][3072][1024] f16 (K-contiguous "B^T")
__global__ void k_trans(const float* __restrict__ src, h16* __restrict__ dst) {
  __shared__ float sT[32][33];
  const int l = blockIdx.z;
  const int n0 = blockIdx.x << 5, k0 = blockIdx.y << 5;
  const int tx = threadIdx.x, ty = threadIdx.y;   // 32 x 8
  const float* s = src + (size_t)l * UNITS * U3;
  h16* d = dst + (size_t)l * U3 * UNITS;
#pragma unroll
  for (int r = 0; r < 4; ++r)
    sT[ty + r * 8][tx] = s[(size_t)(k0 + ty + r * 8) * U3 + n0 + tx];
  __syncthreads();
#pragma unroll
  for (int r = 0; r < 4; ++r)
    d[(size_t)(n0 + ty + r * 8) * UNITS + k0 + tx] = (h16)sT[tx][ty + r * 8];
}

// initial_states [B,U,3] f32 -> h0 [3][B*U] f16
__global__ void k_cvt_h(const float* __restrict__ init, h16* __restrict__ h0) {
  const int idx = blockIdx.x * 256 + threadIdx.x;
  const int l = idx >> 17, r = idx & 131071;
  h0[idx] = (h16)init[(size_t)r * 3 + l];
}

// C[M,3072] = A[M,1024] @ Bt[3072,1024]^T + bias  (m97 structure)
__global__ __launch_bounds__(256) void k_gemm_xw(
    const h16* __restrict__ A, const h16* __restrict__ Bt,
    const float* __restrict__ bias, h16* __restrict__ C) {
  __shared__ __align__(16) h16 sA[128 * 32];
  __shared__ __align__(16) h16 sB[128 * 32];
  const int tid = threadIdx.x;
  const int lane = tid & 63, wave = tid >> 6;
  const int wm = (wave & 1) << 6, wn = (wave >> 1) << 6;
  const int m0 = blockIdx.x << 7;
  const int n0 = blockIdx.y << 7;
  const int crow = tid >> 2, ck = (tid & 3) << 3;
  const int fm = lane & 15, fq = lane >> 4;
  f32x4 acc[4][4] = {};
  for (int k0 = 0; k0 < 1024; k0 += 32) {
    ASYNC16(A + (size_t)(m0 + crow) * 1024 + k0 + ck,      sA + wave * 512);
    ASYNC16(A + (size_t)(m0 + 64 + crow) * 1024 + k0 + ck, sA + 2048 + wave * 512);
    ASYNC16(Bt + (size_t)(n0 + crow) * 1024 + k0 + ck,      sB + wave * 512);
    ASYNC16(Bt + (size_t)(n0 + 64 + crow) * 1024 + k0 + ck, sB + 2048 + wave * 512);
    __syncthreads();
    h16x8 af[4], bfv[4];
#pragma unroll
    for (int i = 0; i < 4; ++i)
      af[i] = *(const h16x8*)(sA + (wm + i * 16 + fm) * 32 + fq * 8);
#pragma unroll
    for (int j = 0; j < 4; ++j)
      bfv[j] = *(const h16x8*)(sB + (wn + j * 16 + fm) * 32 + fq * 8);
#pragma unroll
    for (int i = 0; i < 4; ++i)
#pragma unroll
      for (int j = 0; j < 4; ++j)
        acc[i][j] = __builtin_amdgcn_mfma_f32_16x16x32_f16(af[i], bfv[j], acc[i][j], 0, 0, 0);
    __syncthreads();
  }
#pragma unroll
  for (int j = 0; j < 4; ++j) {
    const int col = n0 + wn + j * 16 + fm;
    const float bv = bias[col];
#pragma unroll
    for (int i = 0; i < 4; ++i) {
      const int row = m0 + wm + i * 16 + fq * 4;
#pragma unroll
      for (int r = 0; r < 4; ++r)
        C[(size_t)(row + r) * U3 + col] = (h16)(acc[i][j][r] + bv);
    }
  }
}

// Persistent recurrence: one launch does all 256 steps of one layer.
// 256 blocks x 128 threads; block = 32 rows x 16 h-cols; U slice (96 KB)
// stays in LDS for all steps; h staged per step in two 32KB halves.
__global__ __launch_bounds__(128) void k_persist(
    const h16* __restrict__ Ut,    // [3072][1024]
    const float* __restrict__ b1,  // [3072]
    const h16* __restrict__ xw,    // [256][128][3072]
    const h16* __restrict__ h0,    // [128][1024]
    h16* __restrict__ hA, h16* __restrict__ hB,
    h16* __restrict__ y16,         // x16 base [T][128][1024] or null
    float* __restrict__ yf,        // d_out [B,T,U] or null
    float* __restrict__ st,        // d_out states + l (stride 3)
    unsigned* __restrict__ bar) {  // 8 sub-counters (x32 u32 apart) + root at [256]
  __shared__ __align__(16) h16 sU[49152];  // 96 KB: [kk=32][g=3][lane=64][8]
  __shared__ __align__(16) h16 sH[16384];  // 32 KB: [mt=2][j=16][lane=64][8]
  const int tid = threadIdx.x;             // 0..127
  const int w = tid >> 6;                  // wave = m-tile
  const int lane = tid & 63;
  const int fm = lane & 15, fq = lane >> 4;
  const int lrow = lane & 15, lhs8 = (lane >> 4) << 3;
  const int b = blockIdx.x;
  const int col0 = (b & 63) << 4;
  const int mrow0 = (b >> 6) << 5;
  const int col = col0 + fm;

  // ---- one-time: stage this block's U slice into LDS (fragment order) ----
#pragma unroll
  for (int i = 0; i < 48; ++i) {
    const int kk = (w << 4) + i / 3, g = i % 3;
    ASYNC16(Ut + (size_t)((g << 10) + col0 + lrow) * 1024 + (kk << 5) + lhs8,
            sU + ((kk * 3 + g) << 9));
  }
  const float bz = b1[col], br = b1[1024 + col], bh = b1[2048 + col];
  __syncthreads();

  for (int t = 0; t < TSTEPS; ++t) {
    const h16* hin = (t == 0) ? h0 : ((t & 1) ? hA : hB);
    h16* hout = (t & 1) ? hB : hA;
    const h16* xwt = xw + (size_t)t * (BATCH * U3);

    // stage h half 0 (kk 0..15) for this wave's m-tile
#pragma unroll
    for (int i = 0; i < 16; ++i)
      ASYNC16(hin + (size_t)(mrow0 + (w << 4) + lrow) * 1024 + (i << 5) + lhs8,
              sH + (((w << 4) + i) << 9));
    // prefetch epilogue scalars (overlaps DMA)
    float hp[4], xz[4], xr_[4], xh[4];
#pragma unroll
    for (int r = 0; r < 4; ++r) {
      const int row = mrow0 + (w << 4) + (fq << 2) + r;
      hp[r]  = (float)hin[(size_t)row * 1024 + col];
      xz[r]  = (float)xwt[(size_t)row * U3 + col];
      xr_[r] = (float)xwt[(size_t)row * U3 + 1024 + col];
      xh[r]  = (float)xwt[(size_t)row * U3 + 2048 + col];
    }
    __syncthreads();

    f32x4 acc0 = {}, acc1 = {}, acc2 = {};
#pragma unroll
    for (int i = 0; i < 16; ++i) {
      const h16x8 a = *(const h16x8*)(sH + (((w << 4) + i) << 9) + (lane << 3));
      acc0 = __builtin_amdgcn_mfma_f32_16x16x32_f16(a, *(const h16x8*)(sU + ((i * 3 + 0) << 9) + (lane << 3)), acc0, 0, 0, 0);
      acc1 = __builtin_amdgcn_mfma_f32_16x16x32_f16(a, *(const h16x8*)(sU + ((i * 3 + 1) << 9) + (lane << 3)), acc1, 0, 0, 0);
      acc2 = __builtin_amdgcn_mfma_f32_16x16x32_f16(a, *(const h16x8*)(sU + ((i * 3 + 2) << 9) + (lane << 3)), acc2, 0, 0, 0);
    }
    __syncthreads();   // waves done with sH half 0 (own-wave data; cheap)

    // stage h half 1 (kk 16..31) into same slots
#pragma unroll
    for (int i = 0; i < 16; ++i)
      ASYNC16(hin + (size_t)(mrow0 + (w << 4) + lrow) * 1024 + ((16 + i) << 5) + lhs8,
              sH + (((w << 4) + i) << 9));
    __syncthreads();

#pragma unroll
    for (int i = 0; i < 16; ++i) {
      const int kk = 16 + i;
      const h16x8 a = *(const h16x8*)(sH + (((w << 4) + i) << 9) + (lane << 3));
      acc0 = __builtin_amdgcn_mfma_f32_16x16x32_f16(a, *(const h16x8*)(sU + ((kk * 3 + 0) << 9) + (lane << 3)), acc0, 0, 0, 0);
      acc1 = __builtin_amdgcn_mfma_f32_16x16x32_f16(a, *(const h16x8*)(sU + ((kk * 3 + 1) << 9) + (lane << 3)), acc1, 0, 0, 0);
      acc2 = __builtin_amdgcn_mfma_f32_16x16x32_f16(a, *(const h16x8*)(sU + ((kk * 3 + 2) << 9) + (lane << 3)), acc2, 0, 0, 0);
    }

    // epilogue: gates + h update + outputs
#pragma unroll
    for (int r = 0; r < 4; ++r) {
      const int row = mrow0 + (w << 4) + (fq << 2) + r;
      const float z  = sigmf(xz[r] + acc0[r] + bz);
      const float rg = sigmf(xr_[r] + acc1[r] + br);
      const float hh = tanhf_fast(xh[r] + rg * (acc2[r] + bh));
      const float hn = z * hp[r] + (1.0f - z) * hh;
      hout[(size_t)row * 1024 + col] = (h16)hn;
      if (y16) y16[(size_t)t * (BATCH * UNITS) + (size_t)row * 1024 + col] = (h16)hn;
      if (yf)  yf[(size_t)(row * 256 + t) * 1024 + col] = hn;
      if (t == TSTEPS - 1) st[(size_t)(row * 1024 + col) * 3] = hn;
    }

    // ---- grid barrier (two-level, monotonic generations) ----
    if (t < TSTEPS - 1) {
      __threadfence();
      __syncthreads();
      if (tid == 0) {
        unsigned* sub  = bar + ((b >> 5) << 5);
        unsigned* root = bar + 256;
        const unsigned old = __hip_atomic_fetch_add(sub, 1u, __ATOMIC_ACQ_REL, __HIP_MEMORY_SCOPE_AGENT);
        if (old == 32u * (unsigned)(t + 1) - 1u)
          __hip_atomic_fetch_add(root, 1u, __ATOMIC_ACQ_REL, __HIP_MEMORY_SCOPE_AGENT);
        while (__hip_atomic_load(root, __ATOMIC_ACQUIRE, __HIP_MEMORY_SCOPE_AGENT) < 8u * (unsigned)(t + 1))
          __builtin_amdgcn_s_sleep(1);
      }
      __syncthreads();
    }
  }
}

extern "C" void kernel_launch(void* const* d_in, const int* in_sizes, int n_in,
                              void* d_out, int out_size, void* d_ws, size_t ws_size,
                              hipStream_t stream) {
  const float* x_in  = (const float*)d_in[0];
  const float* h0_in = (const float*)d_in[1];
  const float* W     = (const float*)d_in[2];
  const float* U     = (const float*)d_in[3];
  const float* bias  = (const float*)d_in[4];
  float* out = (float*)d_out;

  char* ws = (char*)d_ws;
  h16* x16 = (h16*)(ws);                         // [T,B,U]
  h16* xw  = (h16*)(ws + 67108864);              // [T,B,3U]
  h16* Wt  = (h16*)(ws + 268435456);             // [3][3072][1024]
  h16* Ut  = (h16*)(ws + 287309824);             // [3][3072][1024]
  h16* h0b = (h16*)(ws + 306184192);             // [3][128*1024]
  h16* hA  = (h16*)(ws + 306970624);             // ping
  h16* hB  = (h16*)(ws + 307232768);             // pong
  unsigned* bar = (unsigned*)(ws + 307494912);   // 3 x 512 u32

  hipMemsetAsync(bar, 0, 8192, stream);          // ws is poisoned 0xAA each call

  k_cvt_x<<<TSTEPS * BATCH, 256, 0, stream>>>(x_in, x16);
  k_trans<<<dim3(96, 32, 3), dim3(32, 8), 0, stream>>>(W, Wt);
  k_trans<<<dim3(96, 32, 3), dim3(32, 8), 0, stream>>>(U, Ut);
  k_cvt_h<<<1536, 256, 0, stream>>>(h0_in, h0b);

  for (int l = 0; l < 3; ++l) {
    const float* b0 = bias + (size_t)l * 6144;
    const float* b1 = bias + (size_t)l * 6144 + 3072;
    k_gemm_xw<<<dim3(256, 24), 256, 0, stream>>>(x16, Wt + (size_t)l * U3 * UNITS, b0, xw);
    k_persist<<<256, 128, 0, stream>>>(
        Ut + (size_t)l * U3 * UNITS, b1, xw, h0b + (size_t)l * BATCH * UNITS,
        hA, hB,
        (l < 2) ? x16 : nullptr,
        (l == 2) ? out : nullptr,
        out + 33554432 + l,
        bar + (size_t)l * 512);
  }
}